// Round 1
// baseline (200.837 us; speedup 1.0000x reference)
//
#include <hip/hip_runtime.h>
#include <math.h>

#define BB 8
#define CC 96
#define HH 256
#define WW 256
#define HW (HH*WW)

typedef unsigned long long u64;

// ---------------- init min/max ----------------
__global__ void k_init(unsigned* mn_u, unsigned* mx_u) {
    int t = threadIdx.x;
    if (t < BB) { mn_u[t] = 0x7f800000u; mx_u[t] = 0u; }
}

// ---------------- channel mean: x[B,C,H,W] -> m[B,H,W] ----------------
__global__ void k_mean(const float* __restrict__ x, float* __restrict__ m) {
    int i = blockIdx.x * blockDim.x + threadIdx.x;   // per float4 of [B,HW]
    const int per = HW / 4;
    if (i >= BB * per) return;
    int b = i / per, hw4 = i % per;
    const float4* xb = reinterpret_cast<const float4*>(x) + (size_t)b * CC * per + hw4;
    double a0 = 0, a1 = 0, a2 = 0, a3 = 0;
    for (int c = 0; c < CC; ++c) {
        float4 v = xb[(size_t)c * per];
        a0 += (double)v.x; a1 += (double)v.y; a2 += (double)v.z; a3 += (double)v.w;
    }
    float4 o;
    o.x = (float)(a0 / 96.0); o.y = (float)(a1 / 96.0);
    o.z = (float)(a2 / 96.0); o.w = (float)(a3 / 96.0);
    reinterpret_cast<float4*>(m)[i] = o;
}

// ---------------- sobel magnitude + per-image min/max ----------------
__global__ void k_sobel(const float* __restrict__ m, float* __restrict__ mag,
                        unsigned* mn_u, unsigned* mx_u) {
    int row = blockIdx.x;            // b*HH + h  (one row per block)
    int b = row >> 8, h = row & 255, w = threadIdx.x;
    const float* mb = m + (size_t)b * HW;
    auto at = [&](int hh, int ww) -> float {
        if (hh < 0 || hh >= HH || ww < 0 || ww >= WW) return 0.0f;
        return mb[hh * WW + ww];
    };
    float a00 = at(h - 1, w - 1), a01 = at(h - 1, w), a02 = at(h - 1, w + 1);
    float a10 = at(h, w - 1),                         a12 = at(h, w + 1);
    float a20 = at(h + 1, w - 1), a21 = at(h + 1, w), a22 = at(h + 1, w + 1);
    float gx = a00 - a02 + 2.0f * a10 - 2.0f * a12 + a20 - a22;
    float gy = a00 + 2.0f * a01 + a02 - a20 - 2.0f * a21 - a22;
    float mg = sqrtf(gx * gx + gy * gy + 1e-6f);
    mag[row * WW + w] = mg;

    float lmn = mg, lmx = mg;
    for (int off = 32; off; off >>= 1) {
        lmn = fminf(lmn, __shfl_down(lmn, off));
        lmx = fmaxf(lmx, __shfl_down(lmx, off));
    }
    __shared__ float smn[4], smx[4];
    int wv = threadIdx.x >> 6, ln = threadIdx.x & 63;
    if (ln == 0) { smn[wv] = lmn; smx[wv] = lmx; }
    __syncthreads();
    if (threadIdx.x == 0) {
        float bmn = fminf(fminf(smn[0], smn[1]), fminf(smn[2], smn[3]));
        float bmx = fmaxf(fmaxf(smx[0], smx[1]), fmaxf(smx[2], smx[3]));
        atomicMin(&mn_u[b], __float_as_uint(bmn));   // mg > 0 -> uint order == float order
        atomicMax(&mx_u[b], __float_as_uint(bmx));
    }
}

// ---------------- normalize c + half-row partial sums ----------------
__global__ void k_cnorm(const float* __restrict__ mag, const unsigned* __restrict__ mn_u,
                        const unsigned* __restrict__ mx_u, float* __restrict__ c,
                        float* __restrict__ part) {
    int row = blockIdx.x;            // b*HH + h
    int b = row >> 8, w = threadIdx.x;
    float mn = __uint_as_float(mn_u[b]);
    float mx = __uint_as_float(mx_u[b]);
    float rng = mx - mn;
    float mg = mag[row * WW + w];
    float cc = (rng > 0.0f) ? (mg - mn) / (rng + 1e-6f) : 0.0f;
    c[row * WW + w] = cc;

    float r = cc;
    for (int off = 32; off; off >>= 1) r += __shfl_down(r, off);
    __shared__ float s[4];
    int wv = threadIdx.x >> 6, ln = threadIdx.x & 63;
    if (ln == 0) s[wv] = r;
    __syncthreads();
    if (threadIdx.x == 0) {
        part[row * 2 + 0] = s[0] + s[1];   // w in [0,128)
        part[row * 2 + 1] = s[2] + s[3];   // w in [128,256)
    }
}

// ---------------- quadrant means -> base[b][q] ----------------
__global__ void k_base(const float* __restrict__ part, int* __restrict__ base) {
    int t = threadIdx.x;
    if (t >= 32) return;
    int b = t >> 2, q = t & 3;
    int hlo = (q >> 1) ? 128 : 0;    // q: 0=TL 1=TR 2=BL 3=BR
    int col = q & 1;
    double s = 0.0;
    for (int h = hlo; h < hlo + 128; ++h) s += (double)part[(b * HH + h) * 2 + col];
    float rc = (float)(s / 16384.0);
    float sig = 1.0f / (1.0f + expf(-5.0f * (rc - 0.5f)));
    float bs = 5.0f - sig * 4.0f;
    bs = fminf(fmaxf(bs, 1.0f), 5.0f);
    base[b * 4 + q] = (int)rintf(bs);
}

// ---------------- local complexity -> adj[b][h][w] in {-1,0,1} ----------------
__global__ void k_adj(const float* __restrict__ c, signed char* __restrict__ adj) {
    int row = blockIdx.x;            // b*HH + h
    int b = row >> 8, h = row & 255, w = threadIdx.x;
    const float* cb = c + (size_t)b * HW;
    auto at = [&](int hh, int ww) -> float {
        if (hh < 0 || hh >= HH || ww < 0 || ww >= WW) return 0.0f;
        return cb[hh * WW + ww];
    };
    const float w9 = 1.0f / 9.0f;
    float acc = 0.0f;
    acc = fmaf(at(h - 1, w - 1), w9, acc);
    acc = fmaf(at(h - 1, w    ), w9, acc);
    acc = fmaf(at(h - 1, w + 1), w9, acc);
    acc = fmaf(at(h    , w - 1), w9, acc);
    acc = fmaf(at(h    , w    ), w9, acc);
    acc = fmaf(at(h    , w + 1), w9, acc);
    acc = fmaf(at(h + 1, w - 1), w9, acc);
    acc = fmaf(at(h + 1, w    ), w9, acc);
    acc = fmaf(at(h + 1, w + 1), w9, acc);
    float sg = 1.0f / (1.0f + expf(-5.0f * (acc - 0.5f)));
    adj[row * WW + w] = (signed char)(int)rintf(sg * 2.0f - 1.0f);
}

// ---------------- 4-direction adaptive traversal -> bitmasks ----------------
#define SETBIT(j) do { int _j = (j); \
    if (_j < 64) m0 |= 1ull << _j; \
    else if (_j < 128) m1 |= 1ull << (_j - 64); \
    else if (_j < 192) m2 |= 1ull << (_j - 128); \
    else m3 |= 1ull << (_j - 192); } while (0)

__global__ void k_trav(const signed char* __restrict__ adj, const int* __restrict__ base,
                       u64* __restrict__ masks) {
    int tid = blockIdx.x * blockDim.x + threadIdx.x;    // 0..8191
    int dir = tid >> 11;
    int idx = tid & 2047;
    int b = idx >> 8, r = idx & 255;
    int bs = base[b * 4 + dir];
    const signed char* ab = adj + (size_t)b * HW;
    u64 m0 = 0, m1 = 0, m2 = 0, m3 = 0;
    if (dir == 0) {                       // rows, left -> right
        int j = 0;
        while (j < WW) {
            SETBIT(j);
            int st = bs + (int)ab[r * WW + j];
            st = st < 1 ? 1 : (st > 5 ? 5 : st);
            j += st;
        }
    } else if (dir == 1) {                // rows, right -> left
        int j = WW - 1;
        while (j >= 0) {
            SETBIT(j);
            int st = bs + (int)ab[r * WW + j];
            st = st < 1 ? 1 : (st > 5 ? 5 : st);
            j -= st;
        }
    } else if (dir == 2) {                // cols, top -> down
        int j = 0;
        while (j < HH) {
            SETBIT(j);
            int st = bs + (int)ab[j * WW + r];
            st = st < 1 ? 1 : (st > 5 ? 5 : st);
            j += st;
        }
    } else {                              // cols, bottom -> up
        int j = HH - 1;
        while (j >= 0) {
            SETBIT(j);
            int st = bs + (int)ab[j * WW + r];
            st = st < 1 ? 1 : (st > 5 ? 5 : st);
            j -= st;
        }
    }
    u64* o = masks + ((size_t)dir * BB * 256 + idx) * 4;
    o[0] = m0; o[1] = m1; o[2] = m2; o[3] = m3;
}

// ---------------- combine masks -> scale[b][h][w] ----------------
__global__ void k_scale(const u64* __restrict__ masks, float* __restrict__ scale) {
    int row = blockIdx.x;                 // b*HH + h
    int b = row >> 8, h = row & 255, w = threadIdx.x;
    const u64* m0 = masks + (((size_t)0 * BB + b) * 256 + h) * 4;
    const u64* m1 = masks + (((size_t)1 * BB + b) * 256 + h) * 4;
    const u64* m2 = masks + (((size_t)2 * BB + b) * 256 + w) * 4;
    const u64* m3 = masks + (((size_t)3 * BB + b) * 256 + w) * 4;
    int v = (int)((m0[w >> 6] >> (w & 63)) & 1ull)
          + (int)((m1[w >> 6] >> (w & 63)) & 1ull)
          + (int)((m2[h >> 6] >> (h & 63)) & 1ull)
          + (int)((m3[h >> 6] >> (h & 63)) & 1ull);
    float fV = (float)v;
    scale[row * WW + w] = fV / (fV + 1e-6f);
}

// ---------------- output: out = x * scale (broadcast over C) ----------------
__global__ void k_out(const float* __restrict__ x, const float* __restrict__ scale,
                      float* __restrict__ out) {
    const int total4 = BB * CC * HW / 4;
    const int per_img4 = CC * HW / 4;
    const int hw4n = HW / 4;
    const float4* x4 = reinterpret_cast<const float4*>(x);
    const float4* s4 = reinterpret_cast<const float4*>(scale);
    float4* o4 = reinterpret_cast<float4*>(out);
    for (int i = blockIdx.x * blockDim.x + threadIdx.x; i < total4;
         i += gridDim.x * blockDim.x) {
        int b = i / per_img4;
        int hw4 = i % hw4n;
        float4 sv = s4[b * hw4n + hw4];
        float4 xv = x4[i];
        float4 ov;
        ov.x = xv.x * sv.x; ov.y = xv.y * sv.y; ov.z = xv.z * sv.z; ov.w = xv.w * sv.w;
        o4[i] = ov;
    }
}

extern "C" void kernel_launch(void* const* d_in, const int* in_sizes, int n_in,
                              void* d_out, int out_size, void* d_ws, size_t ws_size,
                              hipStream_t stream) {
    const float* x = (const float*)d_in[0];
    float* out = (float*)d_out;
    char* ws = (char*)d_ws;

    // workspace layout (~8.8 MB)
    float* m     = (float*)(ws);                                    // 2 MB
    float* mag   = (float*)(ws + (size_t)2 * 1024 * 1024);          // 2 MB
    float* c     = (float*)(ws + (size_t)4 * 1024 * 1024);          // 2 MB
    float* scale = (float*)(ws + (size_t)6 * 1024 * 1024);          // 2 MB
    signed char* adj = (signed char*)(ws + (size_t)8 * 1024 * 1024);        // 512 KB
    u64* masks   = (u64*)(ws + (size_t)8 * 1024 * 1024 + 524288);           // 256 KB
    float* part  = (float*)(ws + (size_t)8 * 1024 * 1024 + 524288 + 262144);// 16 KB
    unsigned* mn_u = (unsigned*)(ws + (size_t)8 * 1024 * 1024 + 524288 + 262144 + 16384);
    unsigned* mx_u = mn_u + 8;
    int* base = (int*)(mn_u + 16);

    k_init<<<1, 64, 0, stream>>>(mn_u, mx_u);
    k_mean<<<(BB * HW / 4 + 255) / 256, 256, 0, stream>>>(x, m);
    k_sobel<<<BB * HH, 256, 0, stream>>>(m, mag, mn_u, mx_u);
    k_cnorm<<<BB * HH, 256, 0, stream>>>(mag, mn_u, mx_u, c, part);
    k_base<<<1, 32, 0, stream>>>(part, base);
    k_adj<<<BB * HH, 256, 0, stream>>>(c, adj);
    k_trav<<<32, 256, 0, stream>>>(adj, base, masks);
    k_scale<<<BB * HH, 256, 0, stream>>>(masks, scale);
    k_out<<<4096, 256, 0, stream>>>(x, scale, out);
}

// Round 2
// 188.207 us; speedup vs baseline: 1.0671x; 1.0671x over previous
//
#include <hip/hip_runtime.h>
#include <math.h>

#define BB 8
#define CC 96
#define HH 256
#define WW 256
#define HW (HH*WW)

typedef unsigned long long u64;

// ---------------- channel mean: x[B,C,H,W] -> m[B,H,W]  (+ init min/max) ----------------
__global__ void k_mean(const float* __restrict__ x, float* __restrict__ m,
                       unsigned* __restrict__ mn_u, unsigned* __restrict__ mx_u) {
    if (blockIdx.x == 0 && threadIdx.x < 2 * BB) {
        if (threadIdx.x < BB) mn_u[threadIdx.x] = 0x7f800000u;
        else                  mx_u[threadIdx.x - BB] = 0u;
    }
    int i = blockIdx.x * blockDim.x + threadIdx.x;   // per float4 of [B,HW]
    const int per = HW / 4;
    if (i >= BB * per) return;
    int b = i / per, hw4 = i % per;
    const float4* xb = reinterpret_cast<const float4*>(x) + (size_t)b * CC * per + hw4;
    double a0 = 0, a1 = 0, a2 = 0, a3 = 0;
#pragma unroll 8
    for (int c = 0; c < CC; ++c) {
        float4 v = xb[(size_t)c * per];
        a0 += (double)v.x; a1 += (double)v.y; a2 += (double)v.z; a3 += (double)v.w;
    }
    float4 o;
    o.x = (float)(a0 / 96.0); o.y = (float)(a1 / 96.0);
    o.z = (float)(a2 / 96.0); o.w = (float)(a3 / 96.0);
    reinterpret_cast<float4*>(m)[i] = o;
}

// ---------------- sobel magnitude + per-image min/max ----------------
__global__ void k_sobel(const float* __restrict__ m, float* __restrict__ mag,
                        unsigned* mn_u, unsigned* mx_u) {
    int row = blockIdx.x;            // b*HH + h  (one row per block)
    int b = row >> 8, h = row & 255, w = threadIdx.x;
    const float* mb = m + (size_t)b * HW;
    auto at = [&](int hh, int ww) -> float {
        if (hh < 0 || hh >= HH || ww < 0 || ww >= WW) return 0.0f;
        return mb[hh * WW + ww];
    };
    float a00 = at(h - 1, w - 1), a01 = at(h - 1, w), a02 = at(h - 1, w + 1);
    float a10 = at(h, w - 1),                         a12 = at(h, w + 1);
    float a20 = at(h + 1, w - 1), a21 = at(h + 1, w), a22 = at(h + 1, w + 1);
    float gx = a00 - a02 + 2.0f * a10 - 2.0f * a12 + a20 - a22;
    float gy = a00 + 2.0f * a01 + a02 - a20 - 2.0f * a21 - a22;
    float mg = sqrtf(gx * gx + gy * gy + 1e-6f);
    mag[row * WW + w] = mg;

    float lmn = mg, lmx = mg;
    for (int off = 32; off; off >>= 1) {
        lmn = fminf(lmn, __shfl_down(lmn, off));
        lmx = fmaxf(lmx, __shfl_down(lmx, off));
    }
    __shared__ float smn[4], smx[4];
    int wv = threadIdx.x >> 6, ln = threadIdx.x & 63;
    if (ln == 0) { smn[wv] = lmn; smx[wv] = lmx; }
    __syncthreads();
    if (threadIdx.x == 0) {
        float bmn = fminf(fminf(smn[0], smn[1]), fminf(smn[2], smn[3]));
        float bmx = fmaxf(fmaxf(smx[0], smx[1]), fmaxf(smx[2], smx[3]));
        atomicMin(&mn_u[b], __float_as_uint(bmn));   // mg > 0 -> uint order == float order
        atomicMax(&mx_u[b], __float_as_uint(bmx));
    }
}

// ---------------- fused: normalize (recompute per neighbor) -> adj + part ----------------
__global__ void k_adjpart(const float* __restrict__ mag, const unsigned* __restrict__ mn_u,
                          const unsigned* __restrict__ mx_u, signed char* __restrict__ adj,
                          float* __restrict__ part) {
    int row = blockIdx.x;            // b*HH + h
    int b = row >> 8, h = row & 255, w = threadIdx.x;
    float mn = __uint_as_float(mn_u[b]);
    float mx = __uint_as_float(mx_u[b]);
    float rng = mx - mn;
    const float* gb = mag + (size_t)b * HW;
    // identical f32 op sequence to the old stored-c path: (mg-mn)/(rng+1e-6f)
    auto cat = [&](int hh, int ww) -> float {
        if (hh < 0 || hh >= HH || ww < 0 || ww >= WW) return 0.0f;
        float mg = gb[hh * WW + ww];
        return (rng > 0.0f) ? (mg - mn) / (rng + 1e-6f) : 0.0f;
    };
    float cc = cat(h, w);

    // half-row partial sums (same shfl tree as before)
    float r = cc;
    for (int off = 32; off; off >>= 1) r += __shfl_down(r, off);
    __shared__ float s[4];
    int wv = threadIdx.x >> 6, ln = threadIdx.x & 63;
    if (ln == 0) s[wv] = r;
    __syncthreads();
    if (threadIdx.x == 0) {
        part[row * 2 + 0] = s[0] + s[1];   // w in [0,128)
        part[row * 2 + 1] = s[2] + s[3];   // w in [128,256)
    }

    // local complexity -> adj (identical fmaf chain order to old k_adj)
    const float w9 = 1.0f / 9.0f;
    float acc = 0.0f;
    acc = fmaf(cat(h - 1, w - 1), w9, acc);
    acc = fmaf(cat(h - 1, w    ), w9, acc);
    acc = fmaf(cat(h - 1, w + 1), w9, acc);
    acc = fmaf(cat(h    , w - 1), w9, acc);
    acc = fmaf(cc,               w9, acc);
    acc = fmaf(cat(h    , w + 1), w9, acc);
    acc = fmaf(cat(h + 1, w - 1), w9, acc);
    acc = fmaf(cat(h + 1, w    ), w9, acc);
    acc = fmaf(cat(h + 1, w + 1), w9, acc);
    float sg = 1.0f / (1.0f + expf(-5.0f * (acc - 0.5f)));
    adj[row * WW + w] = (signed char)(int)rintf(sg * 2.0f - 1.0f);
}

// ---------------- fused base + 4-direction adaptive traversal -> bitmasks ----------------
#define SETBIT(j) do { int _j = (j); \
    if (_j < 64) m0 |= 1ull << _j; \
    else if (_j < 128) m1 |= 1ull << (_j - 64); \
    else if (_j < 192) m2 |= 1ull << (_j - 128); \
    else m3 |= 1ull << (_j - 192); } while (0)

__global__ void k_travbase(const signed char* __restrict__ adj, const float* __restrict__ part,
                           u64* __restrict__ masks) {
    int blk = blockIdx.x;                 // 0..31, = dir*8 + b
    int dir = blk >> 3, b = blk & 7;
    int t = threadIdx.x;

    // compute base[b][dir] in-block (f64 tree reduce over 128 half-row partials)
    __shared__ double sd[128];
    __shared__ int sbs;
    int hlo = (dir >> 1) ? 128 : 0;
    int col = dir & 1;
    if (t < 128) sd[t] = (double)part[((b << 8) + hlo + t) * 2 + col];
    __syncthreads();
    for (int str = 64; str > 0; str >>= 1) {
        if (t < str) sd[t] += sd[t + str];
        __syncthreads();
    }
    if (t == 0) {
        float rc = (float)(sd[0] / 16384.0);
        float sig = 1.0f / (1.0f + expf(-5.0f * (rc - 0.5f)));
        float bsf = 5.0f - sig * 4.0f;
        bsf = fminf(fmaxf(bsf, 1.0f), 5.0f);
        sbs = (int)rintf(bsf);
    }
    __syncthreads();
    int bs = sbs;

    int r = t;                            // one chain per thread
    const signed char* ab = adj + (size_t)b * HW;
    u64 m0 = 0, m1 = 0, m2 = 0, m3 = 0;
    if (dir == 0) {                       // rows, left -> right
        int j = 0;
        while (j < WW) {
            SETBIT(j);
            int st = bs + (int)ab[r * WW + j];
            st = st < 1 ? 1 : (st > 5 ? 5 : st);
            j += st;
        }
    } else if (dir == 1) {                // rows, right -> left
        int j = WW - 1;
        while (j >= 0) {
            SETBIT(j);
            int st = bs + (int)ab[r * WW + j];
            st = st < 1 ? 1 : (st > 5 ? 5 : st);
            j -= st;
        }
    } else if (dir == 2) {                // cols, top -> down
        int j = 0;
        while (j < HH) {
            SETBIT(j);
            int st = bs + (int)ab[j * WW + r];
            st = st < 1 ? 1 : (st > 5 ? 5 : st);
            j += st;
        }
    } else {                              // cols, bottom -> up
        int j = HH - 1;
        while (j >= 0) {
            SETBIT(j);
            int st = bs + (int)ab[j * WW + r];
            st = st < 1 ? 1 : (st > 5 ? 5 : st);
            j -= st;
        }
    }
    u64* o = masks + ((size_t)dir * BB * 256 + (b << 8) + r) * 4;
    o[0] = m0; o[1] = m1; o[2] = m2; o[3] = m3;
}

// ---------------- combine masks -> scale[b][h][w] ----------------
__global__ void k_scale(const u64* __restrict__ masks, float* __restrict__ scale) {
    int row = blockIdx.x;                 // b*HH + h
    int b = row >> 8, h = row & 255, w = threadIdx.x;
    const u64* m0 = masks + (((size_t)0 * BB + b) * 256 + h) * 4;
    const u64* m1 = masks + (((size_t)1 * BB + b) * 256 + h) * 4;
    const u64* m2 = masks + (((size_t)2 * BB + b) * 256 + w) * 4;
    const u64* m3 = masks + (((size_t)3 * BB + b) * 256 + w) * 4;
    int v = (int)((m0[w >> 6] >> (w & 63)) & 1ull)
          + (int)((m1[w >> 6] >> (w & 63)) & 1ull)
          + (int)((m2[h >> 6] >> (h & 63)) & 1ull)
          + (int)((m3[h >> 6] >> (h & 63)) & 1ull);
    float fV = (float)v;
    scale[row * WW + w] = fV / (fV + 1e-6f);
}

// ---------------- output: out = x * scale (broadcast over C) ----------------
__global__ void k_out(const float* __restrict__ x, const float* __restrict__ scale,
                      float* __restrict__ out) {
    const int total4 = BB * CC * HW / 4;
    const int per_img4 = CC * HW / 4;
    const int hw4n = HW / 4;
    const float4* x4 = reinterpret_cast<const float4*>(x);
    const float4* s4 = reinterpret_cast<const float4*>(scale);
    float4* o4 = reinterpret_cast<float4*>(out);
    for (int i = blockIdx.x * blockDim.x + threadIdx.x; i < total4;
         i += gridDim.x * blockDim.x) {
        int b = i / per_img4;
        int hw4 = i % hw4n;
        float4 sv = s4[b * hw4n + hw4];
        float4 xv = x4[i];
        float4 ov;
        ov.x = xv.x * sv.x; ov.y = xv.y * sv.y; ov.z = xv.z * sv.z; ov.w = xv.w * sv.w;
        o4[i] = ov;
    }
}

extern "C" void kernel_launch(void* const* d_in, const int* in_sizes, int n_in,
                              void* d_out, int out_size, void* d_ws, size_t ws_size,
                              hipStream_t stream) {
    const float* x = (const float*)d_in[0];
    float* out = (float*)d_out;
    char* ws = (char*)d_ws;

    // workspace layout (~7 MB)
    float* m     = (float*)(ws);                                    // 2 MB
    float* mag   = (float*)(ws + (size_t)2 * 1024 * 1024);          // 2 MB
    float* scale = (float*)(ws + (size_t)4 * 1024 * 1024);          // 2 MB
    signed char* adj = (signed char*)(ws + (size_t)6 * 1024 * 1024);        // 512 KB
    u64* masks   = (u64*)(ws + (size_t)6 * 1024 * 1024 + 524288);           // 256 KB
    float* part  = (float*)(ws + (size_t)6 * 1024 * 1024 + 524288 + 262144);// 16 KB
    unsigned* mn_u = (unsigned*)(ws + (size_t)6 * 1024 * 1024 + 524288 + 262144 + 16384);
    unsigned* mx_u = mn_u + 8;

    k_mean<<<(BB * HW / 4 + 255) / 256, 256, 0, stream>>>(x, m, mn_u, mx_u);
    k_sobel<<<BB * HH, 256, 0, stream>>>(m, mag, mn_u, mx_u);
    k_adjpart<<<BB * HH, 256, 0, stream>>>(mag, mn_u, mx_u, adj, part);
    k_travbase<<<32, 256, 0, stream>>>(adj, part, masks);
    k_scale<<<BB * HH, 256, 0, stream>>>(masks, scale);
    k_out<<<4096, 256, 0, stream>>>(x, scale, out);
}

// Round 3
// 168.994 us; speedup vs baseline: 1.1884x; 1.1137x over previous
//
#include <hip/hip_runtime.h>
#include <math.h>

#define BB 8
#define CC 96
#define HH 256
#define WW 256
#define HW (HH*WW)

typedef unsigned long long u64;
typedef float f32x4 __attribute__((ext_vector_type(4)));

// ---------------- channel mean: x[B,C,H,W] -> m[B,H,W]  (+ init min/max) ----------------
// block = (b, tile of 64 float4s); 4 waves, each sums a 24-channel chunk; f64 LDS combine.
__global__ void k_mean(const float* __restrict__ x, float* __restrict__ m,
                       unsigned* __restrict__ mn_u, unsigned* __restrict__ mx_u) {
    if (blockIdx.x == 0 && threadIdx.x < 2 * BB) {
        if (threadIdx.x < BB) mn_u[threadIdx.x] = 0x7f800000u;
        else                  mx_u[threadIdx.x - BB] = 0u;
    }
    int blk = blockIdx.x;                 // b*256 + tile
    int b = blk >> 8, tile = blk & 255;
    int wv = threadIdx.x >> 6, ln = threadIdx.x & 63;
    int hw4 = tile * 64 + ln;             // float4 index within image
    const int per = HW / 4;               // 16384
    const float4* xb = reinterpret_cast<const float4*>(x)
                     + ((size_t)b * CC + wv * 24) * per + hw4;
    double a0 = 0, a1 = 0, a2 = 0, a3 = 0;
#pragma unroll
    for (int c = 0; c < 24; ++c) {
        float4 v = xb[(size_t)c * per];
        a0 += (double)v.x; a1 += (double)v.y; a2 += (double)v.z; a3 += (double)v.w;
    }
    __shared__ double sbuf[4][4][64];
    sbuf[wv][0][ln] = a0; sbuf[wv][1][ln] = a1;
    sbuf[wv][2][ln] = a2; sbuf[wv][3][ln] = a3;
    __syncthreads();
    if (wv == 0) {
        double r0 = sbuf[0][0][ln] + sbuf[1][0][ln] + sbuf[2][0][ln] + sbuf[3][0][ln];
        double r1 = sbuf[0][1][ln] + sbuf[1][1][ln] + sbuf[2][1][ln] + sbuf[3][1][ln];
        double r2 = sbuf[0][2][ln] + sbuf[1][2][ln] + sbuf[2][2][ln] + sbuf[3][2][ln];
        double r3 = sbuf[0][3][ln] + sbuf[1][3][ln] + sbuf[2][3][ln] + sbuf[3][3][ln];
        float4 o;
        o.x = (float)(r0 / 96.0); o.y = (float)(r1 / 96.0);
        o.z = (float)(r2 / 96.0); o.w = (float)(r3 / 96.0);
        reinterpret_cast<float4*>(m)[(size_t)b * per + hw4] = o;
    }
}

// ---------------- sobel magnitude + per-image min/max ----------------
__global__ void k_sobel(const float* __restrict__ m, float* __restrict__ mag,
                        unsigned* mn_u, unsigned* mx_u) {
    int row = blockIdx.x;            // b*HH + h  (one row per block)
    int b = row >> 8, h = row & 255, w = threadIdx.x;
    const float* mb = m + (size_t)b * HW;
    auto at = [&](int hh, int ww) -> float {
        if (hh < 0 || hh >= HH || ww < 0 || ww >= WW) return 0.0f;
        return mb[hh * WW + ww];
    };
    float a00 = at(h - 1, w - 1), a01 = at(h - 1, w), a02 = at(h - 1, w + 1);
    float a10 = at(h, w - 1),                         a12 = at(h, w + 1);
    float a20 = at(h + 1, w - 1), a21 = at(h + 1, w), a22 = at(h + 1, w + 1);
    float gx = a00 - a02 + 2.0f * a10 - 2.0f * a12 + a20 - a22;
    float gy = a00 + 2.0f * a01 + a02 - a20 - 2.0f * a21 - a22;
    float mg = sqrtf(gx * gx + gy * gy + 1e-6f);
    mag[row * WW + w] = mg;

    float lmn = mg, lmx = mg;
    for (int off = 32; off; off >>= 1) {
        lmn = fminf(lmn, __shfl_down(lmn, off));
        lmx = fmaxf(lmx, __shfl_down(lmx, off));
    }
    __shared__ float smn[4], smx[4];
    int wv = threadIdx.x >> 6, ln = threadIdx.x & 63;
    if (ln == 0) { smn[wv] = lmn; smx[wv] = lmx; }
    __syncthreads();
    if (threadIdx.x == 0) {
        float bmn = fminf(fminf(smn[0], smn[1]), fminf(smn[2], smn[3]));
        float bmx = fmaxf(fmaxf(smx[0], smx[1]), fmaxf(smx[2], smx[3]));
        atomicMin(&mn_u[b], __float_as_uint(bmn));   // mg > 0 -> uint order == float order
        atomicMax(&mx_u[b], __float_as_uint(bmx));
    }
}

// ---------------- fused: normalize (recompute per neighbor) -> adj + part ----------------
__global__ void k_adjpart(const float* __restrict__ mag, const unsigned* __restrict__ mn_u,
                          const unsigned* __restrict__ mx_u, signed char* __restrict__ adj,
                          float* __restrict__ part) {
    int row = blockIdx.x;            // b*HH + h
    int b = row >> 8, h = row & 255, w = threadIdx.x;
    float mn = __uint_as_float(mn_u[b]);
    float mx = __uint_as_float(mx_u[b]);
    float rng = mx - mn;
    const float* gb = mag + (size_t)b * HW;
    auto cat = [&](int hh, int ww) -> float {
        if (hh < 0 || hh >= HH || ww < 0 || ww >= WW) return 0.0f;
        float mg = gb[hh * WW + ww];
        return (rng > 0.0f) ? (mg - mn) / (rng + 1e-6f) : 0.0f;
    };
    float cc = cat(h, w);

    float r = cc;
    for (int off = 32; off; off >>= 1) r += __shfl_down(r, off);
    __shared__ float s[4];
    int wv = threadIdx.x >> 6, ln = threadIdx.x & 63;
    if (ln == 0) s[wv] = r;
    __syncthreads();
    if (threadIdx.x == 0) {
        part[row * 2 + 0] = s[0] + s[1];   // w in [0,128)
        part[row * 2 + 1] = s[2] + s[3];   // w in [128,256)
    }

    const float w9 = 1.0f / 9.0f;
    float acc = 0.0f;
    acc = fmaf(cat(h - 1, w - 1), w9, acc);
    acc = fmaf(cat(h - 1, w    ), w9, acc);
    acc = fmaf(cat(h - 1, w + 1), w9, acc);
    acc = fmaf(cat(h    , w - 1), w9, acc);
    acc = fmaf(cc,               w9, acc);
    acc = fmaf(cat(h    , w + 1), w9, acc);
    acc = fmaf(cat(h + 1, w - 1), w9, acc);
    acc = fmaf(cat(h + 1, w    ), w9, acc);
    acc = fmaf(cat(h + 1, w + 1), w9, acc);
    float sg = 1.0f / (1.0f + expf(-5.0f * (acc - 0.5f)));
    adj[row * WW + w] = (signed char)(int)rintf(sg * 2.0f - 1.0f);
}

// ---------------- fused base + 4-direction adaptive traversal -> bitmasks ----------------
#define SETBIT(j) do { int _j = (j); \
    if (_j < 64) m0 |= 1ull << _j; \
    else if (_j < 128) m1 |= 1ull << (_j - 64); \
    else if (_j < 192) m2 |= 1ull << (_j - 128); \
    else m3 |= 1ull << (_j - 192); } while (0)

__global__ void k_travbase(const signed char* __restrict__ adj, const float* __restrict__ part,
                           u64* __restrict__ masks) {
    int blk = blockIdx.x;                 // 0..31, = dir*8 + b
    int dir = blk >> 3, b = blk & 7;
    int t = threadIdx.x;

    __shared__ double sd[128];
    __shared__ int sbs;
    int hlo = (dir >> 1) ? 128 : 0;
    int col = dir & 1;
    if (t < 128) sd[t] = (double)part[((b << 8) + hlo + t) * 2 + col];
    __syncthreads();
    for (int str = 64; str > 0; str >>= 1) {
        if (t < str) sd[t] += sd[t + str];
        __syncthreads();
    }
    if (t == 0) {
        float rc = (float)(sd[0] / 16384.0);
        float sig = 1.0f / (1.0f + expf(-5.0f * (rc - 0.5f)));
        float bsf = 5.0f - sig * 4.0f;
        bsf = fminf(fmaxf(bsf, 1.0f), 5.0f);
        sbs = (int)rintf(bsf);
    }
    __syncthreads();
    int bs = sbs;

    int r = t;
    const signed char* ab = adj + (size_t)b * HW;
    u64 m0 = 0, m1 = 0, m2 = 0, m3 = 0;
    if (dir == 0) {
        int j = 0;
        while (j < WW) {
            SETBIT(j);
            int st = bs + (int)ab[r * WW + j];
            st = st < 1 ? 1 : (st > 5 ? 5 : st);
            j += st;
        }
    } else if (dir == 1) {
        int j = WW - 1;
        while (j >= 0) {
            SETBIT(j);
            int st = bs + (int)ab[r * WW + j];
            st = st < 1 ? 1 : (st > 5 ? 5 : st);
            j -= st;
        }
    } else if (dir == 2) {
        int j = 0;
        while (j < HH) {
            SETBIT(j);
            int st = bs + (int)ab[j * WW + r];
            st = st < 1 ? 1 : (st > 5 ? 5 : st);
            j += st;
        }
    } else {
        int j = HH - 1;
        while (j >= 0) {
            SETBIT(j);
            int st = bs + (int)ab[j * WW + r];
            st = st < 1 ? 1 : (st > 5 ? 5 : st);
            j -= st;
        }
    }
    u64* o = masks + ((size_t)dir * BB * 256 + (b << 8) + r) * 4;
    o[0] = m0; o[1] = m1; o[2] = m2; o[3] = m3;
}

// ---------------- combine masks -> scale[b][h][w] ----------------
__global__ void k_scale(const u64* __restrict__ masks, float* __restrict__ scale) {
    int row = blockIdx.x;                 // b*HH + h
    int b = row >> 8, h = row & 255, w = threadIdx.x;
    const u64* m0 = masks + (((size_t)0 * BB + b) * 256 + h) * 4;
    const u64* m1 = masks + (((size_t)1 * BB + b) * 256 + h) * 4;
    const u64* m2 = masks + (((size_t)2 * BB + b) * 256 + w) * 4;
    const u64* m3 = masks + (((size_t)3 * BB + b) * 256 + w) * 4;
    int v = (int)((m0[w >> 6] >> (w & 63)) & 1ull)
          + (int)((m1[w >> 6] >> (w & 63)) & 1ull)
          + (int)((m2[h >> 6] >> (h & 63)) & 1ull)
          + (int)((m3[h >> 6] >> (h & 63)) & 1ull);
    float fV = (float)v;
    scale[row * WW + w] = fV / (fV + 1e-6f);
}

// ---------------- output: out = x * scale (broadcast over C), nontemporal stores ----------------
__global__ void k_out(const float* __restrict__ x, const float* __restrict__ scale,
                      float* __restrict__ out) {
    const int per_img4 = CC * HW / 4;     // 1572864
    const int hw4n = HW / 4;              // 16384 (pow2)
    int i = blockIdx.x * blockDim.x + threadIdx.x;   // exact cover of total4
    int b = i / per_img4;
    int hw4 = i & (hw4n - 1);
    f32x4 sv = reinterpret_cast<const f32x4*>(scale)[b * hw4n + hw4];
    f32x4 xv = reinterpret_cast<const f32x4*>(x)[i];
    f32x4 ov = xv * sv;
    __builtin_nontemporal_store(ov, reinterpret_cast<f32x4*>(out) + i);
}

extern "C" void kernel_launch(void* const* d_in, const int* in_sizes, int n_in,
                              void* d_out, int out_size, void* d_ws, size_t ws_size,
                              hipStream_t stream) {
    const float* x = (const float*)d_in[0];
    float* out = (float*)d_out;
    char* ws = (char*)d_ws;

    float* m     = (float*)(ws);                                    // 2 MB
    float* mag   = (float*)(ws + (size_t)2 * 1024 * 1024);          // 2 MB
    float* scale = (float*)(ws + (size_t)4 * 1024 * 1024);          // 2 MB
    signed char* adj = (signed char*)(ws + (size_t)6 * 1024 * 1024);        // 512 KB
    u64* masks   = (u64*)(ws + (size_t)6 * 1024 * 1024 + 524288);           // 256 KB
    float* part  = (float*)(ws + (size_t)6 * 1024 * 1024 + 524288 + 262144);// 16 KB
    unsigned* mn_u = (unsigned*)(ws + (size_t)6 * 1024 * 1024 + 524288 + 262144 + 16384);
    unsigned* mx_u = mn_u + 8;

    k_mean<<<BB * 256, 256, 0, stream>>>(x, m, mn_u, mx_u);
    k_sobel<<<BB * HH, 256, 0, stream>>>(m, mag, mn_u, mx_u);
    k_adjpart<<<BB * HH, 256, 0, stream>>>(mag, mn_u, mx_u, adj, part);
    k_travbase<<<32, 256, 0, stream>>>(adj, part, masks);
    k_scale<<<BB * HH, 256, 0, stream>>>(masks, scale);
    k_out<<<(BB * CC * HW / 4) / 256, 256, 0, stream>>>(x, scale, out);
}